// Round 9
// baseline (170.602 us; speedup 1.0000x reference)
//
#include <hip/hip_runtime.h>

typedef __bf16 bf16x8 __attribute__((ext_vector_type(8)));
typedef __bf16 bf16x4 __attribute__((ext_vector_type(4)));
typedef float  f32x4  __attribute__((ext_vector_type(4)));
typedef float  f32x16 __attribute__((ext_vector_type(16)));
typedef unsigned int u32;

#define MFMA_BF16(a, b, c) __builtin_amdgcn_mfma_f32_16x16x32_bf16((a), (b), (c), 0, 0, 0)
#define MFMA32(a, b, c) __builtin_amdgcn_mfma_f32_32x32x16_bf16((a), (b), (c), 0, 0, 0)
#define NEG_INF (-1e30f)
// softmax scale folded with log2(e): exp(s*0.125) == exp2(s*0.125*1.442695)
#define SCL 0.18033688f

__device__ __forceinline__ void gld16(const void* g, void* l) {
  __builtin_amdgcn_global_load_lds(
      (const __attribute__((address_space(1))) void*)g,
      (__attribute__((address_space(3))) void*)l, 16, 0, 0);
}

// ---------------------------------------------------------------------------
// prep: ONE kernel = cast x->bf16 (blocks 0..2047) + transpose w_attn
// (blocks 2048..5119, 96x32 tiles) + transpose w_proj (blocks 5120..6143).
// Replaces 3 launches (saves 2 launch gaps). Branches are block-uniform.
// ---------------------------------------------------------------------------
__global__ __launch_bounds__(256) void prep(
    const float* __restrict__ x, __bf16* __restrict__ xb,
    const float* __restrict__ wa, __bf16* __restrict__ wta,
    const float* __restrict__ wp, __bf16* __restrict__ wtp) {
  __shared__ float t[32][33];
  const int tid = threadIdx.x;
  const int bx = blockIdx.x;
  if (bx < 2048) {  // cast: 8 elems/thread
    int i = (bx * 256 + tid) * 8;
    float4 a = *(const float4*)&x[i];
    float4 b = *(const float4*)&x[i + 4];
    bf16x8 v;
    v[0] = (__bf16)a.x; v[1] = (__bf16)a.y; v[2] = (__bf16)a.z; v[3] = (__bf16)a.w;
    v[4] = (__bf16)b.x; v[5] = (__bf16)b.y; v[6] = (__bf16)b.z; v[7] = (__bf16)b.w;
    *(bf16x8*)&xb[i] = v;
    return;
  }
  const float* in; __bf16* out; int R, C, bxx, byy;
  if (bx < 5120) { in = wa; out = wta; R = 1024; C = 3072;
                   bxx = (bx - 2048) % 96; byy = (bx - 2048) / 96; }
  else           { in = wp; out = wtp; R = 1024; C = 1024;
                   bxx = (bx - 5120) % 32; byy = (bx - 5120) / 32; }
  int tx = tid & 31, ty = tid >> 5;  // 32 x 8
  int xx = bxx * 32 + tx, y0 = byy * 32 + ty;
#pragma unroll
  for (int i = 0; i < 4; ++i)
    t[ty + 8 * i][tx] = in[(size_t)(y0 + 8 * i) * C + xx];
  __syncthreads();
  int x2 = byy * 32 + tx;
#pragma unroll
  for (int i = 0; i < 4; ++i)
    out[(size_t)(bxx * 32 + ty + 8 * i) * R + x2] = (__bf16)t[tx][ty + 8 * i];
}

// ---------------------------------------------------------------------------
// GEMM: C[M][N] = A[M][K]*Bt[N][K]^T + bias[N]. A,Bt bf16, fp32 accum.
// m97 structure + XOR-swizzled LDS (source-permuted gld16; conflict-free).
// Still used for the proj GEMM.
// ---------------------------------------------------------------------------
#define BN 128
#define BK 64

template <int BMT, typename TC>
__global__ __launch_bounds__(256) void gemm_bt_bias(
    const __bf16* __restrict__ A, const __bf16* __restrict__ Bt,
    const float* __restrict__ bias, TC* __restrict__ Cmat,
    int M, int N, int K) {
  constexpr int NI = BMT / 32;  // A chunks per thread; MFMA row-tiles per wave
  __shared__ __align__(16) __bf16 As[BMT * BK];
  __shared__ __align__(16) __bf16 Bs[BN * BK];
  int tid = threadIdx.x;
  int wave = tid >> 6, lane = tid & 63;
  int l16 = lane & 15, quad = lane >> 4;
  int wm = wave >> 1, wn = wave & 1;
  int m0 = blockIdx.y * BMT, n0 = blockIdx.x * BN;

  f32x4 acc[NI][4];
#pragma unroll
  for (int i = 0; i < NI; ++i)
#pragma unroll
    for (int j = 0; j < 4; ++j) acc[i][j] = (f32x4){0.f, 0.f, 0.f, 0.f};

  int row = tid >> 3;                                // 0..31 (+32*i)
  // swizzled source column: slot (tid&7) of row r fetches chunk (tid&7)^(r&7)
  int kc = ((tid & 7) ^ ((tid >> 3) & 7)) * 8;       // i*32 doesn't change r&7
  // fragment-read xor key (elements): chunk cc -> slot cc^(l16&7)
  int xr = (l16 & 7) * 8;

  for (int k0 = 0; k0 < K; k0 += BK) {
#pragma unroll
    for (int i = 0; i < NI; ++i)
      gld16(&A[(size_t)(m0 + row + i * 32) * K + k0 + kc],
            (char*)As + (i * 256 + wave * 64) * 16);
#pragma unroll
    for (int j = 0; j < 4; ++j)
      gld16(&Bt[(size_t)(n0 + row + j * 32) * K + k0 + kc],
            (char*)Bs + (j * 256 + wave * 64) * 16);
    __syncthreads();
#pragma unroll
    for (int ks = 0; ks < 2; ++ks) {
      bf16x8 af[NI], bfr[4];
#pragma unroll
      for (int i = 0; i < NI; ++i)
        af[i] = *(const bf16x8*)&As[(wm * (BMT / 2) + i * 16 + l16) * BK +
                                    ((ks * 32 + quad * 8) ^ xr)];
#pragma unroll
      for (int j = 0; j < 4; ++j)
        bfr[j] = *(const bf16x8*)&Bs[(wn * 64 + j * 16 + l16) * BK +
                                     ((ks * 32 + quad * 8) ^ xr)];
#pragma unroll
      for (int i = 0; i < NI; ++i)
#pragma unroll
        for (int j = 0; j < 4; ++j) acc[i][j] = MFMA_BF16(af[i], bfr[j], acc[i][j]);
    }
    __syncthreads();
  }
  // epilogue: D row = quad*4+r, col = lane&15 within each 16x16 tile
#pragma unroll
  for (int i = 0; i < NI; ++i) {
#pragma unroll
    for (int j = 0; j < 4; ++j) {
      int col = n0 + wn * 64 + j * 16 + l16;
      float bv = bias[col];
#pragma unroll
      for (int r = 0; r < 4; ++r) {
        int rw = m0 + wm * (BMT / 2) + i * 16 + quad * 4 + r;
        Cmat[(size_t)rw * N + col] = (TC)(acc[i][j][r] + bv);
      }
    }
  }
}

// ---------------------------------------------------------------------------
// 4-phase qkv GEMM: C[4096][3072] = A[4096][1024] * Bt[3072][1024]^T + bias.
// 256x192 tile, 512 threads (8 waves, 2M x 4N), BK=64 as two K=32 halves.
// Grid 16x16 = 256 blocks = exactly 1 block/CU.
// Round 9: merged the Mquad phase pairs (8 -> 4 phases/iter, 24 MFMA per
// barrier-pair): same LDS traffic, HALF the barriers (128 -> 64/block). With
// 1 block/CU every barrier stall is exposed -- round-8 budget showed ~12 us
// of barrier overhead vs a ~14 us LDS floor.
// Staging: each phase stages one (buf,ks) A+B pair (4 gld16/lane). Uniform
// WVM8 before every closing barrier = 2 phases of loads in flight; the
// region computed in the NEXT phase was staged 3 phases ago and is provably
// drained. Freshness (compute@ / staged@ / restage@, all one-barrier-after-
// last-read):
//   ph1: compute (0,ks0), stage (1,ks1)<-v    [(1,ks1) last read prev ph4]
//   ph2: compute (0,ks1), stage (0,ks0)<-t2   [last read ph1]
//   ph3: compute (1,ks0), stage (0,ks1)<-t2   [last read ph2]
//   ph4: compute (1,ks1), stage (1,ks0)<-t3   [last read ph3]
// First-iter reads come from the prologue's (0,ks0),(0,ks1),(1,ks0) stages;
// WVM8 drains exactly the right 4 loads at each step (see r9 derivation).
// Epilogue fuses the V transpose: cols >= 2048 go to vt[bh*64+d][t] directly.
// ---------------------------------------------------------------------------
#define BARX do { asm volatile("" ::: "memory"); __builtin_amdgcn_s_barrier(); \
                  asm volatile("" ::: "memory"); } while (0)
#define WLGKM do { asm volatile("s_waitcnt lgkmcnt(0)" ::: "memory"); \
                   __builtin_amdgcn_sched_barrier(0); } while (0)
#define WVM8 asm volatile("s_waitcnt vmcnt(8)" ::: "memory")
#define STA8(SBUF, SKS, T) do { \
    gld16(srcA1 + (size_t)(T) * 64 + (SKS) * 32, (char*)&As[SBUF][SKS][0] + tid * 16); \
    gld16(srcA2 + (size_t)(T) * 64 + (SKS) * 32, (char*)&As[SBUF][SKS][0] + tid * 16 + 8192); \
  } while (0)
#define STB8(SBUF, SKS, T) do { \
    gld16(srcB1 + (size_t)(T) * 64 + (SKS) * 32, (char*)&Bs[SBUF][SKS][0] + tid * 16); \
    gld16(srcB2 + (size_t)(T) * 64 + (SKS) * 32, (char*)&Bs[SBUF][SKS][0] + tid * 16 + 8192); \
  } while (0)
#define LDA8(CBUF, CKS) do { \
    const __bf16* p0_ = &As[CBUF][CKS][(wm * 128 + l16) * 32 + xrd]; \
    af[0] = *(const bf16x8*)(p0_);        af[1] = *(const bf16x8*)(p0_ + 512); \
    af[2] = *(const bf16x8*)(p0_ + 1024); af[3] = *(const bf16x8*)(p0_ + 1536); \
    const __bf16* p1_ = p0_ + 2048; \
    af[4] = *(const bf16x8*)(p1_);        af[5] = *(const bf16x8*)(p1_ + 512); \
    af[6] = *(const bf16x8*)(p1_ + 1024); af[7] = *(const bf16x8*)(p1_ + 1536); \
  } while (0)
#define LDB3(CBUF, CKS) do { \
    const __bf16* p_ = &Bs[CBUF][CKS][(wn * 48 + l16) * 32 + xrd]; \
    bfr[0] = *(const bf16x8*)(p_);       bfr[1] = *(const bf16x8*)(p_ + 512); \
    bfr[2] = *(const bf16x8*)(p_ + 1024); \
  } while (0)
#define MM24 do { \
    __builtin_amdgcn_s_setprio(1); \
    _Pragma("unroll") for (int mi_ = 0; mi_ < 8; ++mi_) \
    _Pragma("unroll") for (int nj_ = 0; nj_ < 3; ++nj_) \
      acc[mi_][nj_] = MFMA_BF16(af[mi_], bfr[nj_], acc[mi_][nj_]); \
    __builtin_amdgcn_s_setprio(0); \
  } while (0)

__global__ __launch_bounds__(512, 2) void gemm_qkv_8ph(
    const __bf16* __restrict__ A, const __bf16* __restrict__ Bt,
    const float* __restrict__ bias, __bf16* __restrict__ qkv,
    __bf16* __restrict__ vt) {
  constexpr int GK = 1024, GN = 3072, NT = 16;  // K, N, K-tiles
  // [buf][khalf][row*32+col]; 16 KiB per region, 128 KiB total.
  __shared__ __align__(16) __bf16 As[2][2][256 * 32];
  __shared__ __align__(16) __bf16 Bs[2][2][256 * 32];  // rows 192..255 = pad
  const int tid = threadIdx.x;
  const int wave = tid >> 6, lane = tid & 63;
  const int l16 = lane & 15, quad = lane >> 4;
  const int wm = wave >> 2, wn = wave & 3;
  const int m0 = blockIdx.y * 256, n0 = blockIdx.x * 192;

  // staging: thread -> (row=tid>>2, slot=tid&3); source chunk = slot^((row>>1)&3)
  const int row0 = tid >> 2;                       // 0..127 (+128 on call 2)
  const int kc = (((tid & 3) ^ ((row0 >> 1) & 3)) * 8);
  // fragment-read xor key: chunk = quad ^ ((row>>1)&3); row>>1 dep reduces to l16
  const int xrd = (quad ^ ((l16 >> 1) & 3)) * 8;

  const __bf16* srcA1 = A + (size_t)(m0 + row0) * GK + kc;
  const __bf16* srcA2 = srcA1 + (size_t)128 * GK;
  const __bf16* srcB1 = Bt + (size_t)(n0 + row0) * GK + kc;
  const int br2 = (row0 + 128 < 192) ? row0 + 128 : 191;  // clamp pad rows
  const __bf16* srcB2 = Bt + (size_t)(n0 + br2) * GK + kc;

  f32x4 acc[8][3];
#pragma unroll
  for (int m = 0; m < 8; ++m)
#pragma unroll
    for (int n = 0; n < 3; ++n) acc[m][n] = (f32x4){0.f, 0.f, 0.f, 0.f};

  // prologue: stage (0,ks0),(0,ks1),(1,ks0); wait so (0,ks0) is landed
  STA8(0, 0, 0); STB8(0, 0, 0);
  STA8(0, 1, 0); STB8(0, 1, 0);
  STA8(1, 0, 1); STB8(1, 0, 1);
  WVM8;
  BARX;

  bf16x8 af[8], bfr[3];
#pragma unroll 1
  for (int i = 0; i < NT / 2; ++i) {
    const int v = 2 * i + 1;
    const int t2 = (2 * i + 2 < NT) ? 2 * i + 2 : NT - 1;  // clamped: junk
    const int t3 = (2 * i + 3 < NT) ? 2 * i + 3 : NT - 1;  // staged, never read
    // ph1: compute (buf0, ks0); stage (1, ks1) <- v
    LDA8(0, 0); LDB3(0, 0); STA8(1, 1, v); STB8(1, 1, v);
    BARX; WLGKM; MM24; WVM8; BARX;
    // ph2: compute (buf0, ks1); stage (0, ks0) <- t2
    LDA8(0, 1); LDB3(0, 1); STA8(0, 0, t2); STB8(0, 0, t2);
    BARX; WLGKM; MM24; WVM8; BARX;
    // ph3: compute (buf1, ks0); stage (0, ks1) <- t2
    LDA8(1, 0); LDB3(1, 0); STA8(0, 1, t2); STB8(0, 1, t2);
    BARX; WLGKM; MM24; WVM8; BARX;
    // ph4: compute (buf1, ks1); stage (1, ks0) <- t3
    LDA8(1, 1); LDB3(1, 1); STA8(1, 0, t3); STB8(1, 0, t3);
    BARX; WLGKM; MM24; WVM8; BARX;
  }

  // epilogue: D row = quad*4+r (M), col = l16 (N). V cols write vt directly.
  // (m*16 == MQ*64 + mi*16 for m = MQ*4+mi, so row mapping is unchanged.)
#pragma unroll
  for (int n = 0; n < 3; ++n) {
    const int c0 = n0 + wn * 48 + n * 16;  // wave-uniform; 2048 is 16-aligned
    const int col = c0 + l16;
    const float bv = bias[col];
    if (c0 < 2048) {
#pragma unroll
      for (int m = 0; m < 8; ++m) {
        const int rw = m0 + wm * 128 + m * 16 + quad * 4;
#pragma unroll
        for (int r = 0; r < 4; ++r)
          qkv[(size_t)(rw + r) * GN + col] = (__bf16)(acc[m][n][r] + bv);
      }
    } else {
      const int h = (col - 2048) >> 6, d = col & 63;
#pragma unroll
      for (int m = 0; m < 8; ++m) {
        const int t0 = m0 + wm * 128 + m * 16 + quad * 4;
        const int b = t0 >> 11, tt = t0 & 2047;
        bf16x4 pb;
#pragma unroll
        for (int r = 0; r < 4; ++r) pb[r] = (__bf16)(acc[m][n][r] + bv);
        *(bf16x4*)&vt[(size_t)((b * 16 + h) * 64 + d) * 2048 + tt] = pb;
      }
    }
  }
}

// ---------------------------------------------------------------------------
// Causal flash attention, 32x32 MFMA, in-register P (no Ps LDS).
// Round 8 structure (kept; measured ~90% of its LDS-pipe roofline):
// 8-wave (512-thr) blocks, waves (qh 0..3, kh 0..1); 512 blocks = 16
// waves/CU at 2 blocks/CU. qb = by<8 ? 15-by : by-8 (big first, CU-paired).
// Per-wave fragment math verified rounds 6-8 (incl. SWAP32 direction).
// ---------------------------------------------------------------------------
#define CVTPK(D, LO, HI) \
  asm("v_cvt_pk_bf16_f32 %0, %1, %2" : "=v"(D) : "v"(LO), "v"(HI))
#define SWAP32(DST, SRC) \
  asm("v_permlane32_swap_b32 %0, %1" : "+v"(DST), "+v"(SRC))

__device__ __forceinline__ bf16x8 mk8(u32 a, u32 b, u32 c, u32 d) {
  union { u32 u[4]; bf16x8 h; } x;
  x.u[0] = a; x.u[1] = b; x.u[2] = c; x.u[3] = d;
  return x.h;
}

__global__ __launch_bounds__(512, 4) void attn_causal(
    const __bf16* __restrict__ qkv, const __bf16* __restrict__ vt,
    __bf16* __restrict__ y) {
  // smem[kv][buf][khalf][64 rows][8 slots x 16B]; 64 KB total.
  __shared__ __align__(16) __bf16 smem[2][2][2][64 * 64];
  const int tid = threadIdx.x;
  const int wave = tid >> 6, lane = tid & 63;
  const int l32 = lane & 31, hi = lane >> 5;
  const int qh = wave >> 1, kh = wave & 1;
  const int bh = blockIdx.x;
  const int b = bh >> 4, h = bh & 15;
  const int RS = 3072;
  const int by = (int)blockIdx.y;
  const int qb = (by < 8) ? 15 - by : by - 8;   // big first; rr-pairs sum 15
  const int nit = qb + 1;                        // 128-key iterations
  const int ktmax = 2 * qb + (qh >> 1);          // last 64-key tile this wave

  // staging: row = tid>>3 (0..63), slot tid&7 holds source chunk
  // slot^(row&7)^((row>>3)&3); one gld16 per thread per 8KB subtile.
  const int row8 = tid >> 3;
  const int kcs = (((tid & 7) ^ (row8 & 7) ^ ((row8 >> 3) & 3)) * 8);
  const __bf16* kbase = qkv + (size_t)(b * 2048) * RS + 1024 + h * 64 + kcs;
  const __bf16* vbase = vt + (size_t)(bh * 64) * 2048 + kcs;
  // fragment-read xor key (chunks); rows l32 and 32+l32 share it
  const int xr = (l32 & 7) ^ ((l32 >> 3) & 3);

  // Q fragments (B-operand): col=q=l32, k=hi*8+e
  const __bf16* qp = qkv +
      (size_t)(b * 2048 + qb * 128 + qh * 32 + l32) * RS + h * 64 + hi * 8;
  bf16x8 qf[4];
#pragma unroll
  for (int kc = 0; kc < 4; ++kc) qf[kc] = *(const bf16x8*)(qp + kc * 16);

  float l4[4] = {0.f, 0.f, 0.f, 0.f};
  f32x16 o0, o1;
#pragma unroll
  for (int r = 0; r < 16; ++r) { o0[r] = 0.f; o1[r] = 0.f; }

  // prologue: stage 128-key tile 0 (both 64-key halves) into buf 0
#pragma unroll
  for (int s = 0; s < 2; ++s) {
    gld16(kbase + (size_t)(s * 64 + row8) * RS, (char*)smem[0][0][s] + tid * 16);
    gld16(vbase + (size_t)row8 * 2048 + s * 64, (char*)smem[1][0][s] + tid * 16);
  }
  __syncthreads();

  for (int it = 0; it < nit; ++it) {
    const int cur = it & 1;
    if (it < qb) {  // guarded prefetch of tile it+1
      const int kb2 = (it + 1) * 128;
#pragma unroll
      for (int s = 0; s < 2; ++s) {
        gld16(kbase + (size_t)(kb2 + s * 64 + row8) * RS,
              (char*)smem[0][cur ^ 1][s] + tid * 16);
        gld16(vbase + (size_t)row8 * 2048 + kb2 + s * 64,
              (char*)smem[1][cur ^ 1][s] + tid * 16);
      }
    }

    const int kt = 2 * it + kh;
    if (kt <= ktmax) {  // wave-uniform skip of fully-masked subtiles
      const __bf16* Kc = smem[0][cur][kh];
      const __bf16* Vc = smem[1][cur][kh];

      // S^T = K Q^T : c[kb][r] = S^T[key=kb*32+(r&3)+8*(r>>2)+4*hi][q=l32]
      f32x16 c0, c1;
#pragma unroll
      for (int r = 0; r < 16; ++r) { c0[r] = 0.f; c1[r] = 0.f; }
      __builtin_amdgcn_s_setprio(1);
#pragma unroll
      for (int kc = 0; kc < 4; ++kc) {
        const int sw = ((kc * 2 + hi) ^ xr) << 3;
        bf16x8 kf0 = *(const bf16x8*)&Kc[l32 * 64 + sw];
        bf16x8 kf1 = *(const bf16x8*)&Kc[(32 + l32) * 64 + sw];
        c0 = MFMA32(kf0, qf[kc], c0);
        c1 = MFMA32(kf1, qf[kc], c1);
      }
      __builtin_amdgcn_s_setprio(0);

      // causal mask only on the diagonal subtile
      if (kt == ktmax) {
        const int qloc = qh * 32 + l32 - (kt - 2 * qb) * 64;
#pragma unroll
        for (int r = 0; r < 16; ++r) {
          const int kl = (r & 3) + 8 * (r >> 2) + 4 * hi;
          if (kl > qloc) c0[r] = NEG_INF;
          if (32 + kl > qloc) c1[r] = NEG_INF;
        }
      }

      // interleaved softmax/PV ladder: SM(kb0) -> PV(kc0,1) -> SM(kb1) -> PV(kc2,3)
      bf16x8 pb[4];
#pragma unroll
      for (int kb = 0; kb < 2; ++kb) {
        float pv[16];
#pragma unroll
        for (int r = 0; r < 16; ++r) {
          const float sv = (kb ? c1[r] : c0[r]);
          pv[r] = __builtin_amdgcn_exp2f(sv * SCL);
          l4[r & 3] += pv[r];
        }
        u32 a0, a1, b0, b1;
        CVTPK(a0, pv[0], pv[1]);   CVTPK(a1, pv[2], pv[3]);
        CVTPK(b0, pv[4], pv[5]);   CVTPK(b1, pv[6], pv[7]);
        SWAP32(a0, b0); SWAP32(a1, b1);
        pb[kb * 2 + 0] = mk8(a0, a1, b0, b1);
        CVTPK(a0, pv[8], pv[9]);   CVTPK(a1, pv[10], pv[11]);
        CVTPK(b0, pv[12], pv[13]); CVTPK(b1, pv[14], pv[15]);
        SWAP32(a0, b0); SWAP32(a1, b1);
        pb[kb * 2 + 1] = mk8(a0, a1, b0, b1);

        // PV for this kb's two key-chunks (kc = kb*2, kb*2+1)
        __builtin_amdgcn_s_setprio(1);
#pragma unroll
        for (int kq = 0; kq < 2; ++kq) {
          const int kc = kb * 2 + kq;
          const int sw = ((kc * 2 + hi) ^ xr) << 3;
          bf16x8 vf0 = *(const bf16x8*)&Vc[l32 * 64 + sw];
          bf16x8 vf1 = *(const bf16x8*)&Vc[(32 + l32) * 64 + sw];
          o0 = MFMA32(vf0, pb[kc], o0);
          o1 = MFMA32(vf1, pb[kc], o1);
        }
        __builtin_amdgcn_s_setprio(0);
      }
    }
    __syncthreads();  // drains this iter's DMA; next tile ready for all waves
  }

  // l: lane owns 32 of each 64-key subtile; partner (lane^32) owns the rest
  float lred = (l4[0] + l4[1]) + (l4[2] + l4[3]);
  lred += __shfl_xor(lred, 32);

  // cross-wave (kh) combine via LDS scratch (aliases K/V buffers; loop done)
  float* sc = (float*)smem;  // o: [qh][2048 floats] in first 32 KB; l after
  if (kh == 1) {
    float* ob = sc + qh * 2048;
#pragma unroll
    for (int r = 0; r < 16; ++r) {
      ob[r * 64 + lane] = o0[r];
      ob[1024 + r * 64 + lane] = o1[r];
    }
    if (lane < 32) sc[8192 + qh * 32 + lane] = lred;
  }
  __syncthreads();
  if (kh == 0) {
    const float* ob = sc + qh * 2048;
    lred += sc[8192 + qh * 32 + l32];
    const float inv = 1.f / lred;
    const int orow = b * 2048 + qb * 128 + qh * 32 + l32;
    __bf16* yb = y + (size_t)orow * 1024 + h * 64 + hi * 4;
#pragma unroll
    for (int db = 0; db < 2; ++db) {
#pragma unroll
      for (int g = 0; g < 4; ++g) {
        bf16x4 w;
#pragma unroll
        for (int j = 0; j < 4; ++j) {
          const float v = (db ? o1[g * 4 + j] : o0[g * 4 + j]) +
                          ob[db * 1024 + (g * 4 + j) * 64 + lane];
          w[j] = (__bf16)(v * inv);
        }
        *(bf16x4*)&yb[db * 32 + g * 8] = w;
      }
    }
  }
}

// ---------------------------------------------------------------------------
extern "C" void kernel_launch(void* const* d_in, const int* in_sizes, int n_in,
                              void* d_out, int out_size, void* d_ws, size_t ws_size,
                              hipStream_t stream) {
  (void)in_sizes; (void)n_in; (void)out_size; (void)ws_size;
  const float* x      = (const float*)d_in[0];  // [2,2048,1024] fp32
  const float* w_attn = (const float*)d_in[1];  // [1024,3072]
  const float* b_attn = (const float*)d_in[2];  // [3072]
  const float* w_proj = (const float*)d_in[3];  // [1024,1024]
  const float* b_proj = (const float*)d_in[4];  // [1024]
  float* out = (float*)d_out;                   // [2,2048,1024] fp32

  __bf16* wt_attn = (__bf16*)d_ws;                       // [3072][1024]
  __bf16* wt_proj = wt_attn + (size_t)3072 * 1024;       // [1024][1024]
  __bf16* qkv     = wt_proj + (size_t)1024 * 1024;       // [4096][3072]
  __bf16* ybuf    = qkv + (size_t)4096 * 3072;           // [4096][1024]
  __bf16* vtbuf   = ybuf + (size_t)4096 * 1024;          // [32*64][2048]

  // x -> bf16 (into ybuf) + both weight transposes, one launch
  prep<<<6144, 256, 0, stream>>>(x, ybuf, w_attn, wt_attn, w_proj, wt_proj);

  // qkv = x @ w_attn + b_attn; V columns written transposed into vtbuf
  // (4-phase 256x192 tile; grid 16x16 = 256 blocks = 1/CU)
  gemm_qkv_8ph<<<dim3(3072 / 192, 4096 / 256), 512, 0, stream>>>(
      ybuf, wt_attn, b_attn, qkv, vtbuf);

  // y = causal_attention(qkv, vt), overwrites ybuf
  // (512 blocks of 512 threads = 16 waves/CU; qb mapped big-first + CU-paired)
  attn_causal<<<dim3(32, 16), 512, 0, stream>>>(qkv, vtbuf, ybuf);

  // out = y @ w_proj + b_proj   (512 blocks, BM=64 for occupancy)
  gemm_bt_bias<64, float><<<dim3(1024 / BN, 4096 / 64), 256, 0, stream>>>(
      ybuf, wt_proj, b_proj, out, 4096, 1024, 1024);
}

// Round 10
// 169.508 us; speedup vs baseline: 1.0065x; 1.0065x over previous
//
#include <hip/hip_runtime.h>

typedef __bf16 bf16x8 __attribute__((ext_vector_type(8)));
typedef __bf16 bf16x4 __attribute__((ext_vector_type(4)));
typedef float  f32x4  __attribute__((ext_vector_type(4)));
typedef float  f32x16 __attribute__((ext_vector_type(16)));
typedef unsigned int u32;

#define MFMA_BF16(a, b, c) __builtin_amdgcn_mfma_f32_16x16x32_bf16((a), (b), (c), 0, 0, 0)
#define MFMA32(a, b, c) __builtin_amdgcn_mfma_f32_32x32x16_bf16((a), (b), (c), 0, 0, 0)
#define NEG_INF (-1e30f)
// softmax scale folded with log2(e): exp(s*0.125) == exp2(s*0.125*1.442695)
#define SCL 0.18033688f

__device__ __forceinline__ void gld16(const void* g, void* l) {
  __builtin_amdgcn_global_load_lds(
      (const __attribute__((address_space(1))) void*)g,
      (__attribute__((address_space(3))) void*)l, 16, 0, 0);
}

// ---------------------------------------------------------------------------
// prep: ONE kernel = cast x->bf16 (blocks 0..2047) + transpose w_attn
// (blocks 2048..5119) + transpose w_proj (blocks 5120..6143).
// ---------------------------------------------------------------------------
__global__ __launch_bounds__(256) void prep(
    const float* __restrict__ x, __bf16* __restrict__ xb,
    const float* __restrict__ wa, __bf16* __restrict__ wta,
    const float* __restrict__ wp, __bf16* __restrict__ wtp) {
  __shared__ float t[32][33];
  const int tid = threadIdx.x;
  const int bx = blockIdx.x;
  if (bx < 2048) {  // cast: 8 elems/thread
    int i = (bx * 256 + tid) * 8;
    float4 a = *(const float4*)&x[i];
    float4 b = *(const float4*)&x[i + 4];
    bf16x8 v;
    v[0] = (__bf16)a.x; v[1] = (__bf16)a.y; v[2] = (__bf16)a.z; v[3] = (__bf16)a.w;
    v[4] = (__bf16)b.x; v[5] = (__bf16)b.y; v[6] = (__bf16)b.z; v[7] = (__bf16)b.w;
    *(bf16x8*)&xb[i] = v;
    return;
  }
  const float* in; __bf16* out; int R, C, bxx, byy;
  if (bx < 5120) { in = wa; out = wta; R = 1024; C = 3072;
                   bxx = (bx - 2048) % 96; byy = (bx - 2048) / 96; }
  else           { in = wp; out = wtp; R = 1024; C = 1024;
                   bxx = (bx - 5120) % 32; byy = (bx - 5120) / 32; }
  int tx = tid & 31, ty = tid >> 5;  // 32 x 8
  int xx = bxx * 32 + tx, y0 = byy * 32 + ty;
#pragma unroll
  for (int i = 0; i < 4; ++i)
    t[ty + 8 * i][tx] = in[(size_t)(y0 + 8 * i) * C + xx];
  __syncthreads();
  int x2 = byy * 32 + tx;
#pragma unroll
  for (int i = 0; i < 4; ++i)
    out[(size_t)(bxx * 32 + ty + 8 * i) * R + x2] = (__bf16)t[tx][ty + 8 * i];
}

// ---------------------------------------------------------------------------
// GEMM: C[M][N] = A[M][K]*Bt[N][K]^T + bias[N]. A,Bt bf16, fp32 accum.
// m97 structure + XOR-swizzled LDS. Still used for the proj GEMM.
// ---------------------------------------------------------------------------
#define BN 128
#define BK 64

template <int BMT, typename TC>
__global__ __launch_bounds__(256) void gemm_bt_bias(
    const __bf16* __restrict__ A, const __bf16* __restrict__ Bt,
    const float* __restrict__ bias, TC* __restrict__ Cmat,
    int M, int N, int K) {
  constexpr int NI = BMT / 32;  // A chunks per thread; MFMA row-tiles per wave
  __shared__ __align__(16) __bf16 As[BMT * BK];
  __shared__ __align__(16) __bf16 Bs[BN * BK];
  int tid = threadIdx.x;
  int wave = tid >> 6, lane = tid & 63;
  int l16 = lane & 15, quad = lane >> 4;
  int wm = wave >> 1, wn = wave & 1;
  int m0 = blockIdx.y * BMT, n0 = blockIdx.x * BN;

  f32x4 acc[NI][4];
#pragma unroll
  for (int i = 0; i < NI; ++i)
#pragma unroll
    for (int j = 0; j < 4; ++j) acc[i][j] = (f32x4){0.f, 0.f, 0.f, 0.f};

  int row = tid >> 3;                                // 0..31 (+32*i)
  int kc = ((tid & 7) ^ ((tid >> 3) & 7)) * 8;       // source-permuted col
  int xr = (l16 & 7) * 8;                            // frag-read xor key

  for (int k0 = 0; k0 < K; k0 += BK) {
#pragma unroll
    for (int i = 0; i < NI; ++i)
      gld16(&A[(size_t)(m0 + row + i * 32) * K + k0 + kc],
            (char*)As + (i * 256 + wave * 64) * 16);
#pragma unroll
    for (int j = 0; j < 4; ++j)
      gld16(&Bt[(size_t)(n0 + row + j * 32) * K + k0 + kc],
            (char*)Bs + (j * 256 + wave * 64) * 16);
    __syncthreads();
#pragma unroll
    for (int ks = 0; ks < 2; ++ks) {
      bf16x8 af[NI], bfr[4];
#pragma unroll
      for (int i = 0; i < NI; ++i)
        af[i] = *(const bf16x8*)&As[(wm * (BMT / 2) + i * 16 + l16) * BK +
                                    ((ks * 32 + quad * 8) ^ xr)];
#pragma unroll
      for (int j = 0; j < 4; ++j)
        bfr[j] = *(const bf16x8*)&Bs[(wn * 64 + j * 16 + l16) * BK +
                                     ((ks * 32 + quad * 8) ^ xr)];
#pragma unroll
      for (int i = 0; i < NI; ++i)
#pragma unroll
        for (int j = 0; j < 4; ++j) acc[i][j] = MFMA_BF16(af[i], bfr[j], acc[i][j]);
    }
    __syncthreads();
  }
#pragma unroll
  for (int i = 0; i < NI; ++i) {
#pragma unroll
    for (int j = 0; j < 4; ++j) {
      int col = n0 + wn * 64 + j * 16 + l16;
      float bv = bias[col];
#pragma unroll
      for (int r = 0; r < 4; ++r) {
        int rw = m0 + wm * (BMT / 2) + i * 16 + quad * 4 + r;
        Cmat[(size_t)rw * N + col] = (TC)(acc[i][j][r] + bv);
      }
    }
  }
}

// ---------------------------------------------------------------------------
// 4-phase qkv GEMM, round 10: 128x192 tile -> LDS 80 KB -> 2 BLOCKS/CU.
// Round-9 falsified "barrier count" (halving barriers was neutral); the
// exposed cost at 1 block/CU is the per-phase lgkm/vmcnt/barrier LATENCY with
// nothing to fill it. 2 blocks/CU lets one block's drain hide under the
// other's MFMA/DMA -- the mechanism measured in attn (rounds 6->8).
//   - grid 16x32 = 512 blocks; bid%8 = bx%8 -> B panels stay XCD-local.
//   - 8 waves = 2(wm) x 4(wn); per wave 64x48 output, acc[4][3].
//   - staging/phase: A = 1 gld16/lane (128 rows); B = 1 gld16/lane (rows
//     0..127) + second gld16 for waves 0..3 (rows 128..191; row key
//     (128+r)>>1 & 3 == r>>1 & 3 since 128 % 8 == 0 -> same swizzle).
//   - wave-conditional counted wait (vmcnt is per-wave): waves 0-3 issue 3
//     loads/phase -> vmcnt(6); waves 4-7 issue 2 -> vmcnt(4). Both = exactly
//     2 phases in flight; cross-wave freshness proof unchanged (staged at
//     phase p, own-count proven at p+2, barrier, read at p+3).
// Epilogue fuses V transpose (cols >= 2048 -> vt), same as before.
// ---------------------------------------------------------------------------
#define BARX do { asm volatile("" ::: "memory"); __builtin_amdgcn_s_barrier(); \
                  asm volatile("" ::: "memory"); } while (0)
#define WLGKM do { asm volatile("s_waitcnt lgkmcnt(0)" ::: "memory"); \
                   __builtin_amdgcn_sched_barrier(0); } while (0)
#define WVMC do { if (wave < 4) asm volatile("s_waitcnt vmcnt(6)" ::: "memory"); \
                  else          asm volatile("s_waitcnt vmcnt(4)" ::: "memory"); } while (0)
#define STA(SBUF, SKS, T) \
    gld16(srcA1 + (size_t)(T) * 64 + (SKS) * 32, (char*)&As[SBUF][SKS][0] + tid * 16)
#define STB(SBUF, SKS, T) do { \
    gld16(srcB1 + (size_t)(T) * 64 + (SKS) * 32, (char*)&Bs[SBUF][SKS][0] + tid * 16); \
    if (wave < 4) \
      gld16(srcB2 + (size_t)(T) * 64 + (SKS) * 32, \
            (char*)&Bs[SBUF][SKS][0] + 8192 + tid * 16); \
  } while (0)
#define LDA4(CBUF, CKS) do { \
    const __bf16* p_ = &As[CBUF][CKS][(wm * 64 + l16) * 32 + xrd]; \
    af[0] = *(const bf16x8*)(p_);        af[1] = *(const bf16x8*)(p_ + 512); \
    af[2] = *(const bf16x8*)(p_ + 1024); af[3] = *(const bf16x8*)(p_ + 1536); \
  } while (0)
#define LDB3(CBUF, CKS) do { \
    const __bf16* p_ = &Bs[CBUF][CKS][(wn * 48 + l16) * 32 + xrd]; \
    bfr[0] = *(const bf16x8*)(p_);       bfr[1] = *(const bf16x8*)(p_ + 512); \
    bfr[2] = *(const bf16x8*)(p_ + 1024); \
  } while (0)
#define MM12 do { \
    __builtin_amdgcn_s_setprio(1); \
    _Pragma("unroll") for (int mi_ = 0; mi_ < 4; ++mi_) \
    _Pragma("unroll") for (int nj_ = 0; nj_ < 3; ++nj_) \
      acc[mi_][nj_] = MFMA_BF16(af[mi_], bfr[nj_], acc[mi_][nj_]); \
    __builtin_amdgcn_s_setprio(0); \
  } while (0)

__global__ __launch_bounds__(512, 4) void gemm_qkv_8ph(
    const __bf16* __restrict__ A, const __bf16* __restrict__ Bt,
    const float* __restrict__ bias, __bf16* __restrict__ qkv,
    __bf16* __restrict__ vt) {
  constexpr int GK = 1024, GN = 3072, NT = 16;  // K, N, K-tiles
  // [buf][khalf]: A region 128x32 (8 KB), B region 192x32 (12 KB); 80 KB.
  __shared__ __align__(16) __bf16 As[2][2][128 * 32];
  __shared__ __align__(16) __bf16 Bs[2][2][192 * 32];
  const int tid = threadIdx.x;
  const int wave = tid >> 6, lane = tid & 63;
  const int l16 = lane & 15, quad = lane >> 4;
  const int wm = wave >> 2, wn = wave & 3;
  const int m0 = blockIdx.y * 128, n0 = blockIdx.x * 192;

  // staging: thread -> (row=tid>>2 in 0..127, slot=tid&3);
  // source chunk = slot ^ ((row>>1)&3)
  const int row0 = tid >> 2;
  const int kc = (((tid & 3) ^ ((row0 >> 1) & 3)) * 8);
  // fragment-read xor key: chunk = quad ^ ((l16>>1)&3)
  const int xrd = (quad ^ ((l16 >> 1) & 3)) * 8;

  const __bf16* srcA1 = A + (size_t)(m0 + row0) * GK + kc;
  const __bf16* srcB1 = Bt + (size_t)(n0 + row0) * GK + kc;
  // B rows 128..191, staged by waves 0..3 (tid<256 -> row0<64); same kc key
  const __bf16* srcB2 = Bt + (size_t)(n0 + 128 + (row0 & 63)) * GK + kc;

  f32x4 acc[4][3];
#pragma unroll
  for (int m = 0; m < 4; ++m)
#pragma unroll
    for (int n = 0; n < 3; ++n) acc[m][n] = (f32x4){0.f, 0.f, 0.f, 0.f};

  // prologue: stage (0,ks0),(0,ks1),(1,ks0); wait so (0,ks0) is landed
  STA(0, 0, 0); STB(0, 0, 0);
  STA(0, 1, 0); STB(0, 1, 0);
  STA(1, 0, 1); STB(1, 0, 1);
  WVMC;
  BARX;

  bf16x8 af[4], bfr[3];
#pragma unroll 1
  for (int i = 0; i < NT / 2; ++i) {
    const int v = 2 * i + 1;
    const int t2 = (2 * i + 2 < NT) ? 2 * i + 2 : NT - 1;  // clamped: junk
    const int t3 = (2 * i + 3 < NT) ? 2 * i + 3 : NT - 1;  // staged, never read
    // ph1: compute (buf0, ks0); stage (1, ks1) <- v
    LDA4(0, 0); LDB3(0, 0); STA(1, 1, v); STB(1, 1, v);
    BARX; WLGKM; MM12; WVMC; BARX;
    // ph2: compute (buf0, ks1); stage (0, ks0) <- t2
    LDA4(0, 1); LDB3(0, 1); STA(0, 0, t2); STB(0, 0, t2);
    BARX; WLGKM; MM12; WVMC; BARX;
    // ph3: compute (buf1, ks0); stage (0, ks1) <- t2
    LDA4(1, 0); LDB3(1, 0); STA(0, 1, t2); STB(0, 1, t2);
    BARX; WLGKM; MM12; WVMC; BARX;
    // ph4: compute (buf1, ks1); stage (1, ks0) <- t3
    LDA4(1, 1); LDB3(1, 1); STA(1, 0, t3); STB(1, 0, t3);
    BARX; WLGKM; MM12; WVMC; BARX;
  }

  // epilogue: D row = quad*4+r (M), col = l16 (N). V cols write vt directly.
#pragma unroll
  for (int n = 0; n < 3; ++n) {
    const int c0 = n0 + wn * 48 + n * 16;  // wave-uniform; 2048 is 16-aligned
    const int col = c0 + l16;
    const float bv = bias[col];
    if (c0 < 2048) {
#pragma unroll
      for (int m = 0; m < 4; ++m) {
        const int rw = m0 + wm * 64 + m * 16 + quad * 4;
#pragma unroll
        for (int r = 0; r < 4; ++r)
          qkv[(size_t)(rw + r) * GN + col] = (__bf16)(acc[m][n][r] + bv);
      }
    } else {
      const int h = (col - 2048) >> 6, d = col & 63;
#pragma unroll
      for (int m = 0; m < 4; ++m) {
        const int t0 = m0 + wm * 64 + m * 16 + quad * 4;
        const int b = t0 >> 11, tt = t0 & 2047;
        bf16x4 pb;
#pragma unroll
        for (int r = 0; r < 4; ++r) pb[r] = (__bf16)(acc[m][n][r] + bv);
        *(bf16x4*)&vt[(size_t)((b * 16 + h) * 64 + d) * 2048 + tt] = pb;
      }
    }
  }
}

// ---------------------------------------------------------------------------
// Causal flash attention, 32x32 MFMA, in-register P (no Ps LDS).
// Round 8 structure (kept; ~90% of its LDS-pipe roofline): 8-wave blocks,
// waves (qh 0..3, kh 0..1); 512 blocks = 16 waves/CU at 2 blocks/CU.
// qb = by<8 ? 15-by : by-8. Fragment math verified rounds 6-8.
// ---------------------------------------------------------------------------
#define CVTPK(D, LO, HI) \
  asm("v_cvt_pk_bf16_f32 %0, %1, %2" : "=v"(D) : "v"(LO), "v"(HI))
#define SWAP32(DST, SRC) \
  asm("v_permlane32_swap_b32 %0, %1" : "+v"(DST), "+v"(SRC))

__device__ __forceinline__ bf16x8 mk8(u32 a, u32 b, u32 c, u32 d) {
  union { u32 u[4]; bf16x8 h; } x;
  x.u[0] = a; x.u[1] = b; x.u[2] = c; x.u[3] = d;
  return x.h;
}

__global__ __launch_bounds__(512, 4) void attn_causal(
    const __bf16* __restrict__ qkv, const __bf16* __restrict__ vt,
    __bf16* __restrict__ y) {
  // smem[kv][buf][khalf][64 rows][8 slots x 16B]; 64 KB total.
  __shared__ __align__(16) __bf16 smem[2][2][2][64 * 64];
  const int tid = threadIdx.x;
  const int wave = tid >> 6, lane = tid & 63;
  const int l32 = lane & 31, hi = lane >> 5;
  const int qh = wave >> 1, kh = wave & 1;
  const int bh = blockIdx.x;
  const int b = bh >> 4, h = bh & 15;
  const int RS = 3072;
  const int by = (int)blockIdx.y;
  const int qb = (by < 8) ? 15 - by : by - 8;   // big first; rr-pairs sum 15
  const int nit = qb + 1;                        // 128-key iterations
  const int ktmax = 2 * qb + (qh >> 1);          // last 64-key tile this wave

  const int row8 = tid >> 3;
  const int kcs = (((tid & 7) ^ (row8 & 7) ^ ((row8 >> 3) & 3)) * 8);
  const __bf16* kbase = qkv + (size_t)(b * 2048) * RS + 1024 + h * 64 + kcs;
  const __bf16* vbase = vt + (size_t)(bh * 64) * 2048 + kcs;
  const int xr = (l32 & 7) ^ ((l32 >> 3) & 3);

  // Q fragments (B-operand): col=q=l32, k=hi*8+e
  const __bf16* qp = qkv +
      (size_t)(b * 2048 + qb * 128 + qh * 32 + l32) * RS + h * 64 + hi * 8;
  bf16x8 qf[4];
#pragma unroll
  for (int kc = 0; kc < 4; ++kc) qf[kc] = *(const bf16x8*)(qp + kc * 16);

  float l4[4] = {0.f, 0.f, 0.f, 0.f};
  f32x16 o0, o1;
#pragma unroll
  for (int r = 0; r < 16; ++r) { o0[r] = 0.f; o1[r] = 0.f; }

  // prologue: stage 128-key tile 0 (both 64-key halves) into buf 0
#pragma unroll
  for (int s = 0; s < 2; ++s) {
    gld16(kbase + (size_t)(s * 64 + row8) * RS, (char*)smem[0][0][s] + tid * 16);
    gld16(vbase + (size_t)row8 * 2048 + s * 64, (char*)smem[1][0][s] + tid * 16);
  }
  __syncthreads();

  for (int it = 0; it < nit; ++it) {
    const int cur = it & 1;
    if (it < qb) {  // guarded prefetch of tile it+1
      const int kb2 = (it + 1) * 128;
#pragma unroll
      for (int s = 0; s < 2; ++s) {
        gld16(kbase + (size_t)(kb2 + s * 64 + row8) * RS,
              (char*)smem[0][cur ^ 1][s] + tid * 16);
        gld16(vbase + (size_t)row8 * 2048 + kb2 + s * 64,
              (char*)smem[1][cur ^ 1][s] + tid * 16);
      }
    }

    const int kt = 2 * it + kh;
    if (kt <= ktmax) {  // wave-uniform skip of fully-masked subtiles
      const __bf16* Kc = smem[0][cur][kh];
      const __bf16* Vc = smem[1][cur][kh];

      // S^T = K Q^T : c[kb][r] = S^T[key=kb*32+(r&3)+8*(r>>2)+4*hi][q=l32]
      f32x16 c0, c1;
#pragma unroll
      for (int r = 0; r < 16; ++r) { c0[r] = 0.f; c1[r] = 0.f; }
      __builtin_amdgcn_s_setprio(1);
#pragma unroll
      for (int kc = 0; kc < 4; ++kc) {
        const int sw = ((kc * 2 + hi) ^ xr) << 3;
        bf16x8 kf0 = *(const bf16x8*)&Kc[l32 * 64 + sw];
        bf16x8 kf1 = *(const bf16x8*)&Kc[(32 + l32) * 64 + sw];
        c0 = MFMA32(kf0, qf[kc], c0);
        c1 = MFMA32(kf1, qf[kc], c1);
      }
      __builtin_amdgcn_s_setprio(0);

      // causal mask only on the diagonal subtile
      if (kt == ktmax) {
        const int qloc = qh * 32 + l32 - (kt - 2 * qb) * 64;
#pragma unroll
        for (int r = 0; r < 16; ++r) {
          const int kl = (r & 3) + 8 * (r >> 2) + 4 * hi;
          if (kl > qloc) c0[r] = NEG_INF;
          if (32 + kl > qloc) c1[r] = NEG_INF;
        }
      }

      // interleaved softmax/PV ladder: SM(kb0) -> PV(kc0,1) -> SM(kb1) -> PV(kc2,3)
      bf16x8 pb[4];
#pragma unroll
      for (int kb = 0; kb < 2; ++kb) {
        float pv[16];
#pragma unroll
        for (int r = 0; r < 16; ++r) {
          const float sv = (kb ? c1[r] : c0[r]);
          pv[r] = __builtin_amdgcn_exp2f(sv * SCL);
          l4[r & 3] += pv[r];
        }
        u32 a0, a1, b0, b1;
        CVTPK(a0, pv[0], pv[1]);   CVTPK(a1, pv[2], pv[3]);
        CVTPK(b0, pv[4], pv[5]);   CVTPK(b1, pv[6], pv[7]);
        SWAP32(a0, b0); SWAP32(a1, b1);
        pb[kb * 2 + 0] = mk8(a0, a1, b0, b1);
        CVTPK(a0, pv[8], pv[9]);   CVTPK(a1, pv[10], pv[11]);
        CVTPK(b0, pv[12], pv[13]); CVTPK(b1, pv[14], pv[15]);
        SWAP32(a0, b0); SWAP32(a1, b1);
        pb[kb * 2 + 1] = mk8(a0, a1, b0, b1);

        // PV for this kb's two key-chunks (kc = kb*2, kb*2+1)
        __builtin_amdgcn_s_setprio(1);
#pragma unroll
        for (int kq = 0; kq < 2; ++kq) {
          const int kc = kb * 2 + kq;
          const int sw = ((kc * 2 + hi) ^ xr) << 3;
          bf16x8 vf0 = *(const bf16x8*)&Vc[l32 * 64 + sw];
          bf16x8 vf1 = *(const bf16x8*)&Vc[(32 + l32) * 64 + sw];
          o0 = MFMA32(vf0, pb[kc], o0);
          o1 = MFMA32(vf1, pb[kc], o1);
        }
        __builtin_amdgcn_s_setprio(0);
      }
    }
    __syncthreads();  // drains this iter's DMA; next tile ready for all waves
  }

  // l: lane owns 32 of each 64-key subtile; partner (lane^32) owns the rest
  float lred = (l4[0] + l4[1]) + (l4[2] + l4[3]);
  lred += __shfl_xor(lred, 32);

  // cross-wave (kh) combine via LDS scratch (aliases K/V buffers; loop done)
  float* sc = (float*)smem;  // o: [qh][2048 floats] in first 32 KB; l after
  if (kh == 1) {
    float* ob = sc + qh * 2048;
#pragma unroll
    for (int r = 0; r < 16; ++r) {
      ob[r * 64 + lane] = o0[r];
      ob[1024 + r * 64 + lane] = o1[r];
    }
    if (lane < 32) sc[8192 + qh * 32 + lane] = lred;
  }
  __syncthreads();
  if (kh == 0) {
    const float* ob = sc + qh * 2048;
    lred += sc[8192 + qh * 32 + l32];
    const float inv = 1.f / lred;
    const int orow = b * 2048 + qb * 128 + qh * 32 + l32;
    __bf16* yb = y + (size_t)orow * 1024 + h * 64 + hi * 4;
#pragma unroll
    for (int db = 0; db < 2; ++db) {
#pragma unroll
      for (int g = 0; g < 4; ++g) {
        bf16x4 w;
#pragma unroll
        for (int j = 0; j < 4; ++j) {
          const float v = (db ? o1[g * 4 + j] : o0[g * 4 + j]) +
                          ob[db * 1024 + (g * 4 + j) * 64 + lane];
          w[j] = (__bf16)(v * inv);
        }
        *(bf16x4*)&yb[db * 32 + g * 8] = w;
      }
    }
  }
}

// ---------------------------------------------------------------------------
extern "C" void kernel_launch(void* const* d_in, const int* in_sizes, int n_in,
                              void* d_out, int out_size, void* d_ws, size_t ws_size,
                              hipStream_t stream) {
  (void)in_sizes; (void)n_in; (void)out_size; (void)ws_size;
  const float* x      = (const float*)d_in[0];  // [2,2048,1024] fp32
  const float* w_attn = (const float*)d_in[1];  // [1024,3072]
  const float* b_attn = (const float*)d_in[2];  // [3072]
  const float* w_proj = (const float*)d_in[3];  // [1024,1024]
  const float* b_proj = (const float*)d_in[4];  // [1024]
  float* out = (float*)d_out;                   // [2,2048,1024] fp32

  __bf16* wt_attn = (__bf16*)d_ws;                       // [3072][1024]
  __bf16* wt_proj = wt_attn + (size_t)3072 * 1024;       // [1024][1024]
  __bf16* qkv     = wt_proj + (size_t)1024 * 1024;       // [4096][3072]
  __bf16* ybuf    = qkv + (size_t)4096 * 3072;           // [4096][1024]
  __bf16* vtbuf   = ybuf + (size_t)4096 * 1024;          // [32*64][2048]

  // x -> bf16 (into ybuf) + both weight transposes, one launch
  prep<<<6144, 256, 0, stream>>>(x, ybuf, w_attn, wt_attn, w_proj, wt_proj);

  // qkv = x @ w_attn + b_attn; V columns written transposed into vtbuf
  // (4-phase 128x192 tile; grid 16x32 = 512 blocks = 2/CU)
  gemm_qkv_8ph<<<dim3(3072 / 192, 4096 / 128), 512, 0, stream>>>(
      ybuf, wt_attn, b_attn, qkv, vtbuf);

  // y = causal_attention(qkv, vt), overwrites ybuf
  // (512 blocks of 512 threads = 16 waves/CU; qb mapped big-first + CU-paired)
  attn_causal<<<dim3(32, 16), 512, 0, stream>>>(qkv, vtbuf, ybuf);

  // out = y @ w_proj + b_proj   (512 blocks, BM=64 for occupancy)
  gemm_bt_bias<64, float><<<dim3(1024 / BN, 4096 / 64), 256, 0, stream>>>(
      ybuf, wt_proj, b_proj, out, 4096, 1024, 1024);
}